// Round 2
// baseline (668.964 us; speedup 1.0000x reference)
//
#include <hip/hip_runtime.h>
#include <hip/hip_bf16.h>
#include <stdint.h>

// Problem constants (FujiSparseMoE): S=2048 B=2 D=1024 E=64 K=2 I=512 SI=512 CAP=256
#define T_TOK 4096
#define DDIM  1024
#define NEXP  64
#define IDIM  512
#define SIDIM 512
#define CAP   256

typedef __attribute__((ext_vector_type(4))) float f32x4;
typedef __attribute__((ext_vector_type(8))) short bf16x8;   // 8 bf16 raw (4 VGPRs)

// 8 fp32 -> 8 bf16 (RNE) via packed converts
__device__ __forceinline__ bf16x8 cvt8(f32x4 a, f32x4 b) {
    union { __hip_bfloat162 h[4]; bf16x8 v; } u;
    u.h[0] = __float22bfloat162_rn(make_float2(a[0], a[1]));
    u.h[1] = __float22bfloat162_rn(make_float2(a[2], a[3]));
    u.h[2] = __float22bfloat162_rn(make_float2(b[0], b[1]));
    u.h[3] = __float22bfloat162_rn(make_float2(b[2], b[3]));
    return u.v;
}
__device__ __forceinline__ short f2bs(float f) {
    union { __hip_bfloat16 h; short s; } u; u.h = __float2bfloat16(f); return u.s;
}

// async global->LDS, 16B per lane; LDS dest is wave-uniform base + lane*16
__device__ __forceinline__ void gload16(const void* g, void* l) {
    __builtin_amdgcn_global_load_lds((const __attribute__((address_space(1))) void*)g,
                                     (__attribute__((address_space(3))) void*)l, 16, 0, 0);
}

// fp32 LDS tile: rows of 32 fp32 (128 B = 8 sixteen-byte slots), source pre-swizzled slot^(row&7).
// Returns bf16 fragment for k = s*8 .. s*8+7 of the given row.
__device__ __forceinline__ bf16x8 frag32(const char* reg0, int row, int s) {
    const char* p = reg0 + row * 128;
    int sw = row & 7;
    f32x4 lo = *(const f32x4*)(p + (((2 * s) ^ sw) << 4));
    f32x4 hi = *(const f32x4*)(p + (((2 * s + 1) ^ sw) << 4));
    return cvt8(lo, hi);
}

// ---------------- logits partials (fp32 exact): lpart[kz][T,E], kz splits K in 4
__global__ __launch_bounds__(256) void logits_kernel(const float* __restrict__ X,
                                                     const float* __restrict__ RW,
                                                     float* __restrict__ lpart) {
    __shared__ float sX[64 * 33];
    __shared__ float sW[64 * 33];
    int m0 = blockIdx.x * 64;
    int kz = blockIdx.y;               // 0..3
    int kbase = kz * 256;
    int tid = threadIdx.x;
    int tg = tid >> 4;                 // 16 groups -> rows tg*4..+4
    int eg = tid & 15;                 // experts eg*4..+4
    float acc[4][4] = {};
    for (int k0 = 0; k0 < 256; k0 += 32) {
        __syncthreads();
#pragma unroll
        for (int i = 0; i < 8; ++i) {
            int idx = i * 256 + tid;   // 0..2047
            int r = idx >> 5, c = idx & 31;
            sX[r * 33 + c] = X[(size_t)(m0 + r) * DDIM + kbase + k0 + c];
            sW[r * 33 + c] = RW[(size_t)r * DDIM + kbase + k0 + c];
        }
        __syncthreads();
#pragma unroll 4
        for (int k = 0; k < 32; ++k) {
            float xv[4], wv[4];
#pragma unroll
            for (int i = 0; i < 4; ++i) xv[i] = sX[(tg * 4 + i) * 33 + k];
#pragma unroll
            for (int j = 0; j < 4; ++j) wv[j] = sW[(eg * 4 + j) * 33 + k];
#pragma unroll
            for (int i = 0; i < 4; ++i)
#pragma unroll
                for (int j = 0; j < 4; ++j) acc[i][j] += xv[i] * wv[j];
        }
    }
    float* outp = lpart + (size_t)kz * T_TOK * NEXP;
#pragma unroll
    for (int i = 0; i < 4; ++i)
#pragma unroll
        for (int j = 0; j < 4; ++j)
            outp[(size_t)(m0 + tg * 4 + i) * NEXP + eg * 4 + j] = acc[i][j];
}

// ---------------- softmax + top2 + dispatch + probs out (fp32) + shared sigmoid gate
__global__ __launch_bounds__(256) void topk_kernel(const float* __restrict__ lpart,
                                                   const float* __restrict__ X,
                                                   const float* __restrict__ SEG,
                                                   float* __restrict__ probs_out,
                                                   int* __restrict__ counts,
                                                   int* __restrict__ tok_slot,
                                                   float* __restrict__ w_slot,
                                                   float* __restrict__ gate_sh) {
    int lane = threadIdx.x & 63;
    int wv   = threadIdx.x >> 6;
    int t    = blockIdx.x * 4 + wv;            // one wave per token, lane = expert
    size_t li = (size_t)t * NEXP + lane;
    float l = lpart[li] + lpart[(size_t)T_TOK * NEXP + li]
            + lpart[2 * (size_t)T_TOK * NEXP + li] + lpart[3 * (size_t)T_TOK * NEXP + li];
    float mx = l;
    for (int s = 32; s; s >>= 1) mx = fmaxf(mx, __shfl_xor(mx, s));
    float e = __expf(l - mx);
    float sum = e;
    for (int s = 32; s; s >>= 1) sum += __shfl_xor(sum, s);
    float prob = e / sum;
    probs_out[li] = prob;
    float v = prob; int idx = lane;
    for (int s = 32; s; s >>= 1) {
        float ov = __shfl_xor(v, s); int oi = __shfl_xor(idx, s);
        if (ov > v || (ov == v && oi < idx)) { v = ov; idx = oi; }
    }
    float v1 = v; int i1 = idx;
    v = (lane == i1) ? -1e30f : prob; idx = lane;
    for (int s = 32; s; s >>= 1) {
        float ov = __shfl_xor(v, s); int oi = __shfl_xor(idx, s);
        if (ov > v || (ov == v && oi < idx)) { v = ov; idx = oi; }
    }
    float v2 = v; int i2 = idx;
    float denom = v1 + v2 + 1e-9f;
    if (lane == 0) {
        int s1 = atomicAdd(&counts[i1], 1);
        if (s1 < CAP) { tok_slot[i1 * CAP + s1] = t; w_slot[i1 * CAP + s1] = v1 / denom; }
        int s2 = atomicAdd(&counts[i2], 1);
        if (s2 < CAP) { tok_slot[i2 * CAP + s2] = t; w_slot[i2 * CAP + s2] = v2 / denom; }
    }
    float g = 0.f;
    const float* xr = X + (size_t)t * DDIM + lane * 16;
    const float* sr = SEG + lane * 16;
#pragma unroll
    for (int j = 0; j < 4; ++j) {
        f32x4 xv = *(const f32x4*)(xr + j * 4);
        f32x4 sv = *(const f32x4*)(sr + j * 4);
#pragma unroll
        for (int q = 0; q < 4; ++q) g += xv[q] * sv[q];
    }
    for (int s = 32; s; s >>= 1) g += __shfl_xor(g, s);
    if (lane == 0) gate_sh[t] = 1.f / (1.f + __expf(-g));
}

// ---------------- fused gate/up GEMM + SwiGLU -> act (bf16)
// BM=128, BN=64 (g and u each), BK=32, 4 waves (2x2), wave tile 64x32.
// fp32 tiles staged to LDS via global_load_lds (async), source-XOR-swizzled,
// double-buffered; converted to bf16 at fragment read.
// LDS/stage: A 16K | Bg 8K | Bu 8K = 32K; x2 buffers = 64K.
template <bool EXPERT>
__global__ __launch_bounds__(256, 2) void gateup_kernel(const float* __restrict__ X,
                                                        const float* __restrict__ Wg_base,
                                                        const float* __restrict__ Wu_base,
                                                        const int* __restrict__ counts,
                                                        const int* __restrict__ tok_slot,
                                                        short* __restrict__ act_out) {
    __shared__ char smem[2 * 32768];
    int e  = EXPERT ? blockIdx.z : 0;
    int m0 = blockIdx.y * 128;
    int n0 = blockIdx.x * 64;
    int M;
    const float *Wg, *Wu;
    if (EXPERT) {
        M = counts[e]; if (M > CAP) M = CAP;
        if (m0 >= M) return;
        const float* base = Wg_base + (size_t)e * (2 * IDIM) * DDIM;
        Wg = base; Wu = base + (size_t)IDIM * DDIM;
    } else {
        M = T_TOK; Wg = Wg_base; Wu = Wu_base;
    }
    int tid = threadIdx.x, lane = tid & 63, wv = tid >> 6;
    int wm = wv >> 1, wn = wv & 1;

    // staging chunk geometry: slot idx = t*256 + tid, 16 B each.
    // t=0..3: A rows (row = t*32 + tid/8), t=4,5: Bg, t=6,7: Bu.
    int srow8 = tid >> 3;                       // row-within-32 for fp32 chunks
    int scol  = (tid & 7) ^ (srow8 & 7);        // source-swizzled 16B slot
    const float* gp[8];
#pragma unroll
    for (int t = 0; t < 4; ++t) {
        int row = t * 32 + srow8;               // A-tile row 0..127
        int grow;
        if (EXPERT) {
            int rr = m0 + row; if (rr >= M) rr = M - 1;
            grow = tok_slot[e * CAP + rr];
        } else grow = m0 + row;
        gp[t] = X + (size_t)grow * DDIM + scol * 4;
    }
#pragma unroll
    for (int t = 0; t < 2; ++t) {
        int row = t * 32 + srow8;               // B-tile row 0..63
        gp[4 + t] = Wg + (size_t)(n0 + row) * DDIM + scol * 4;
        gp[6 + t] = Wu + (size_t)(n0 + row) * DDIM + scol * 4;
    }

    auto issue = [&](int buf) {
        char* lb = smem + buf * 32768 + wv * 1024;
#pragma unroll
        for (int t = 0; t < 8; ++t) {
            gload16(gp[t], lb + t * 4096);
            gp[t] += 32;                        // next 32-K stage (128 B)
        }
    };

    int fm = lane & 15, s = lane >> 4;
    f32x4 accg[4][2] = {}, accu[4][2] = {};
    auto compute = [&](int buf) {
        const char* bb = smem + buf * 32768;
        bf16x8 bg[2], bu[2];
#pragma unroll
        for (int nt = 0; nt < 2; ++nt) {
            int row = wn * 32 + nt * 16 + fm;
            bg[nt] = frag32(bb + 16384, row, s);
            bu[nt] = frag32(bb + 24576, row, s);
        }
#pragma unroll
        for (int mt = 0; mt < 4; ++mt) {
            int row = wm * 64 + mt * 16 + fm;
            bf16x8 a = frag32(bb, row, s);
#pragma unroll
            for (int nt = 0; nt < 2; ++nt) {
                accg[mt][nt] = __builtin_amdgcn_mfma_f32_16x16x32_bf16(a, bg[nt], accg[mt][nt], 0, 0, 0);
                accu[mt][nt] = __builtin_amdgcn_mfma_f32_16x16x32_bf16(a, bu[nt], accu[mt][nt], 0, 0, 0);
            }
        }
    };

    issue(0);
#pragma unroll 1
    for (int kt = 0; kt < 32; kt += 2) {        // DDIM/32 = 32 stages
        __syncthreads();                        // drains vmcnt -> buf0 ready
        issue(1);
        compute(0);
        __syncthreads();                        // buf1 ready
        if (kt + 2 < 32) issue(0);
        compute(1);
    }

    int frow = (lane >> 4) * 4, fcol = lane & 15;
    size_t out_base = EXPERT ? (size_t)e * CAP * IDIM : 0;
#pragma unroll
    for (int mt = 0; mt < 4; ++mt)
#pragma unroll
        for (int r = 0; r < 4; ++r) {
            int row = m0 + wm * 64 + mt * 16 + frow + r;
            if (row < M) {
#pragma unroll
                for (int nt = 0; nt < 2; ++nt) {
                    float g = accg[mt][nt][r];
                    float u = accu[mt][nt][r];
                    float a = (g / (1.f + __expf(-g))) * u;      // silu(g)*u
                    act_out[out_base + (size_t)row * IDIM + (n0 + wn * 32 + nt * 16 + fcol)] = f2bs(a);
                }
            }
        }
}

// ---------------- down GEMM (A bf16, W fp32) + scaled write to out (fp32)
// BM=128, BN=128, BK=32, 4 waves (2x2), wave tile 64x64.
// A (bf16) + W (fp32) staged via global_load_lds, double-buffered.
// LDS/stage: A 8K | B 16K = 24K; x2 buffers = 48K.
// EXPERT: atomicAdd(out);  shared: plain store (initializes out).
template <bool EXPERT>
__global__ __launch_bounds__(256, 3) void down_kernel(const short* __restrict__ A_base,
                                                      const float* __restrict__ W_base,
                                                      const int* __restrict__ counts,
                                                      const int* __restrict__ tok_slot,
                                                      const float* __restrict__ w_slot,
                                                      const float* __restrict__ gate_sh,
                                                      float* __restrict__ out) {
    __shared__ char smem[2 * 24576];
    const int KD = IDIM;  // 512 both paths
    int e  = EXPERT ? blockIdx.z : 0;
    int m0 = blockIdx.y * 128;
    int n0 = blockIdx.x * 128;
    int M;
    const short* A;
    const float* W;
    if (EXPERT) {
        M = counts[e]; if (M > CAP) M = CAP;
        if (m0 >= M) return;
        A = A_base + (size_t)e * CAP * IDIM;
        W = W_base + (size_t)e * DDIM * IDIM;
    } else { M = T_TOK; A = A_base; W = W_base; }
    int tid = threadIdx.x, lane = tid & 63, wv = tid >> 6;
    int wm = wv >> 1, wn = wv & 1;

    // staging: slot idx = t*256 + tid. t=0,1: A bf16 (4 slots/row, row = t*64 + tid/4);
    // t=2..5: B fp32 (8 slots/row, row = (t-2)*32 + tid/8).
    const short* ap[2];
#pragma unroll
    for (int t = 0; t < 2; ++t) {
        int row = t * 64 + (tid >> 2);
        int col = (tid & 3) ^ ((tid >> 2) & 3);   // source-swizzled 16B slot (4/row)
        ap[t] = A + (size_t)(m0 + row) * KD + col * 8;
    }
    const float* bp[4];
    {
        int srow8 = tid >> 3;
        int col = (tid & 7) ^ (srow8 & 7);
#pragma unroll
        for (int t = 0; t < 4; ++t) {
            int row = t * 32 + srow8;
            bp[t] = W + (size_t)(n0 + row) * KD + col * 4;
        }
    }

    auto issue = [&](int buf) {
        char* lb = smem + buf * 24576 + wv * 1024;
#pragma unroll
        for (int t = 0; t < 2; ++t) {
            gload16(ap[t], lb + t * 4096);
            ap[t] += 32;                        // 32 bf16 = 64 B per stage
        }
#pragma unroll
        for (int t = 0; t < 4; ++t) {
            gload16(bp[t], lb + 8192 + t * 4096);
            bp[t] += 32;                        // 32 fp32 = 128 B per stage
        }
    };

    int fm = lane & 15, s = lane >> 4;
    f32x4 acc[4][4] = {};
    auto compute = [&](int buf) {
        const char* bb = smem + buf * 24576;
        bf16x8 b[4];
#pragma unroll
        for (int nt = 0; nt < 4; ++nt) {
            int row = wn * 64 + nt * 16 + fm;
            b[nt] = frag32(bb + 8192, row, s);
        }
#pragma unroll
        for (int mt = 0; mt < 4; ++mt) {
            int row = wm * 64 + mt * 16 + fm;
            bf16x8 a = *(const bf16x8*)(bb + row * 64 + ((s ^ (row & 3)) << 4));
#pragma unroll
            for (int nt = 0; nt < 4; ++nt)
                acc[mt][nt] = __builtin_amdgcn_mfma_f32_16x16x32_bf16(a, b[nt], acc[mt][nt], 0, 0, 0);
        }
    };

    issue(0);
#pragma unroll 1
    for (int kt = 0; kt < 16; kt += 2) {        // KD/32 = 16 stages
        __syncthreads();
        issue(1);
        compute(0);
        __syncthreads();
        if (kt + 2 < 16) issue(0);
        compute(1);
    }

    int frow = (lane >> 4) * 4, fcol = lane & 15;
#pragma unroll
    for (int mt = 0; mt < 4; ++mt)
#pragma unroll
        for (int r = 0; r < 4; ++r) {
            int row = m0 + wm * 64 + mt * 16 + frow + r;
            if (row >= M) continue;
            float scale; int trow;
            if (EXPERT) { scale = w_slot[e * CAP + row]; trow = tok_slot[e * CAP + row]; }
            else        { scale = gate_sh[row];          trow = row; }
#pragma unroll
            for (int nt = 0; nt < 4; ++nt) {
                int col = n0 + wn * 64 + nt * 16 + fcol;
                float vv = acc[mt][nt][r] * scale;
                if (EXPERT) atomicAdd(&out[(size_t)trow * DDIM + col], vv);
                else        out[(size_t)trow * DDIM + col] = vv;
            }
        }
}

extern "C" void kernel_launch(void* const* d_in, const int* in_sizes, int n_in,
                              void* d_out, int out_size, void* d_ws, size_t ws_size,
                              hipStream_t stream) {
    const float* X   = (const float*)d_in[0];   // hidden_states  [T, D] fp32
    const float* RW  = (const float*)d_in[1];   // router_w       [E, D]
    const float* GUP = (const float*)d_in[2];   // gate_up_proj   [E, 2I, D]
    const float* DW  = (const float*)d_in[3];   // down_proj      [E, D, I]
    const float* SG  = (const float*)d_in[4];   // sh_gate_w      [SI, D]
    const float* SU  = (const float*)d_in[5];   // sh_up_w        [SI, D]
    const float* SD  = (const float*)d_in[6];   // sh_down_w      [D, SI]
    const float* SEG = (const float*)d_in[7];   // sh_expert_gate_w [1, D]
    float* out = (float*)d_out;                 // [T*D] out, then [T*E] probs (fp32)

    char* ws = (char*)d_ws;
    size_t off = 0;
    float* lpart    = (float*)(ws + off); off += 4 * (size_t)T_TOK * NEXP * 4;  // 4 MB
    int*   counts   = (int*)  (ws + off); off += 1024;
    int*   tok_slot = (int*)  (ws + off); off += (size_t)NEXP * CAP * 4;        // 64 KB
    float* w_slot   = (float*)(ws + off); off += (size_t)NEXP * CAP * 4;        // 64 KB
    float* gate_sh  = (float*)(ws + off); off += (size_t)T_TOK * 4;             // 16 KB
    short* act      = (short*)(ws + off); off += (size_t)NEXP * CAP * IDIM * 2; // 16 MB
    short* act_sh   = (short*)(ws + off); off += (size_t)T_TOK * SIDIM * 2;     // 4 MB
    (void)ws_size; (void)in_sizes; (void)n_in; (void)out_size;

    hipMemsetAsync(counts, 0, NEXP * sizeof(int), stream);
    logits_kernel<<<dim3(T_TOK / 64, 4), 256, 0, stream>>>(X, RW, lpart);
    topk_kernel<<<T_TOK / 4, 256, 0, stream>>>(lpart, X, SEG,
                                               out + (size_t)T_TOK * DDIM,
                                               counts, tok_slot, w_slot, gate_sh);
    gateup_kernel<false><<<dim3(SIDIM / 64, T_TOK / 128, 1), 256, 0, stream>>>(
        X, SG, SU, nullptr, nullptr, act_sh);
    gateup_kernel<true><<<dim3(IDIM / 64, CAP / 128, NEXP), 256, 0, stream>>>(
        X, GUP, GUP, counts, tok_slot, act);
    down_kernel<false><<<dim3(DDIM / 128, T_TOK / 128, 1), 256, 0, stream>>>(
        act_sh, SD, nullptr, nullptr, nullptr, gate_sh, out);
    down_kernel<true><<<dim3(DDIM / 128, CAP / 128, NEXP), 256, 0, stream>>>(
        act, DW, counts, tok_slot, w_slot, nullptr, out);
}

// Round 3
// 649.172 us; speedup vs baseline: 1.0305x; 1.0305x over previous
//
#include <hip/hip_runtime.h>
#include <hip/hip_bf16.h>
#include <stdint.h>

// Problem constants (FujiSparseMoE): S=2048 B=2 D=1024 E=64 K=2 I=512 SI=512 CAP=256
#define T_TOK 4096
#define DDIM  1024
#define NEXP  64
#define IDIM  512
#define SIDIM 512
#define CAP   256
#define KZ    8     // logits K-split

typedef __attribute__((ext_vector_type(4))) float f32x4;
typedef __attribute__((ext_vector_type(8))) short bf16x8;   // 8 bf16 raw (4 VGPRs)

// 8 fp32 -> 8 bf16 (RNE) via packed converts
__device__ __forceinline__ bf16x8 cvt8(f32x4 a, f32x4 b) {
    union { __hip_bfloat162 h[4]; bf16x8 v; } u;
    u.h[0] = __float22bfloat162_rn(make_float2(a[0], a[1]));
    u.h[1] = __float22bfloat162_rn(make_float2(a[2], a[3]));
    u.h[2] = __float22bfloat162_rn(make_float2(b[0], b[1]));
    u.h[3] = __float22bfloat162_rn(make_float2(b[2], b[3]));
    return u.v;
}
__device__ __forceinline__ short f2bs(float f) {
    union { __hip_bfloat16 h; short s; } u; u.h = __float2bfloat16(f); return u.s;
}

// async global->LDS, 16B per lane; LDS dest is wave-uniform base + lane*16
__device__ __forceinline__ void gload16(const void* g, void* l) {
    __builtin_amdgcn_global_load_lds((const __attribute__((address_space(1))) void*)g,
                                     (__attribute__((address_space(3))) void*)l, 16, 0, 0);
}

// fp32 LDS tile: rows of 32 fp32 (128 B = 8 sixteen-byte slots), source pre-swizzled slot^(row&7).
// Returns bf16 fragment for k = s*8 .. s*8+7 of the given row.
__device__ __forceinline__ bf16x8 frag32(const char* reg0, int row, int s) {
    const char* p = reg0 + row * 128;
    int sw = row & 7;
    f32x4 lo = *(const f32x4*)(p + (((2 * s) ^ sw) << 4));
    f32x4 hi = *(const f32x4*)(p + (((2 * s + 1) ^ sw) << 4));
    return cvt8(lo, hi);
}

// ---------------- logits partials (fp32 exact): lpart[kz][T,E], kz splits K in 8
__global__ __launch_bounds__(256) void logits_kernel(const float* __restrict__ X,
                                                     const float* __restrict__ RW,
                                                     float* __restrict__ lpart) {
    __shared__ float sX[64 * 33];
    __shared__ float sW[64 * 33];
    int m0 = blockIdx.x * 64;
    int kz = blockIdx.y;               // 0..7
    int kbase = kz * (DDIM / KZ);      // 128 K each
    int tid = threadIdx.x;
    int tg = tid >> 4;                 // 16 groups -> rows tg*4..+4
    int eg = tid & 15;                 // experts eg*4..+4
    float acc[4][4] = {};
    for (int k0 = 0; k0 < DDIM / KZ; k0 += 32) {
        __syncthreads();
#pragma unroll
        for (int i = 0; i < 8; ++i) {
            int idx = i * 256 + tid;   // 0..2047
            int r = idx >> 5, c = idx & 31;
            sX[r * 33 + c] = X[(size_t)(m0 + r) * DDIM + kbase + k0 + c];
            sW[r * 33 + c] = RW[(size_t)r * DDIM + kbase + k0 + c];
        }
        __syncthreads();
#pragma unroll 4
        for (int k = 0; k < 32; ++k) {
            float xv[4], wv[4];
#pragma unroll
            for (int i = 0; i < 4; ++i) xv[i] = sX[(tg * 4 + i) * 33 + k];
#pragma unroll
            for (int j = 0; j < 4; ++j) wv[j] = sW[(eg * 4 + j) * 33 + k];
#pragma unroll
            for (int i = 0; i < 4; ++i)
#pragma unroll
                for (int j = 0; j < 4; ++j) acc[i][j] += xv[i] * wv[j];
        }
    }
    float* outp = lpart + (size_t)kz * T_TOK * NEXP;
#pragma unroll
    for (int i = 0; i < 4; ++i)
#pragma unroll
        for (int j = 0; j < 4; ++j)
            outp[(size_t)(m0 + tg * 4 + i) * NEXP + eg * 4 + j] = acc[i][j];
}

// ---------------- softmax + top2 + dispatch + probs out (fp32) + shared sigmoid gate
__global__ __launch_bounds__(256) void topk_kernel(const float* __restrict__ lpart,
                                                   const float* __restrict__ X,
                                                   const float* __restrict__ SEG,
                                                   float* __restrict__ probs_out,
                                                   int* __restrict__ counts,
                                                   int* __restrict__ tok_slot,
                                                   float* __restrict__ w_slot,
                                                   float* __restrict__ gate_sh) {
    int lane = threadIdx.x & 63;
    int wv   = threadIdx.x >> 6;
    int t    = blockIdx.x * 4 + wv;            // one wave per token, lane = expert
    size_t li = (size_t)t * NEXP + lane;
    float l = 0.f;
#pragma unroll
    for (int z = 0; z < KZ; ++z) l += lpart[(size_t)z * T_TOK * NEXP + li];
    float mx = l;
    for (int s = 32; s; s >>= 1) mx = fmaxf(mx, __shfl_xor(mx, s));
    float e = __expf(l - mx);
    float sum = e;
    for (int s = 32; s; s >>= 1) sum += __shfl_xor(sum, s);
    float prob = e / sum;
    probs_out[li] = prob;
    float v = prob; int idx = lane;
    for (int s = 32; s; s >>= 1) {
        float ov = __shfl_xor(v, s); int oi = __shfl_xor(idx, s);
        if (ov > v || (ov == v && oi < idx)) { v = ov; idx = oi; }
    }
    float v1 = v; int i1 = idx;
    v = (lane == i1) ? -1e30f : prob; idx = lane;
    for (int s = 32; s; s >>= 1) {
        float ov = __shfl_xor(v, s); int oi = __shfl_xor(idx, s);
        if (ov > v || (ov == v && oi < idx)) { v = ov; idx = oi; }
    }
    float v2 = v; int i2 = idx;
    float denom = v1 + v2 + 1e-9f;
    if (lane == 0) {
        int s1 = atomicAdd(&counts[i1], 1);
        if (s1 < CAP) { tok_slot[i1 * CAP + s1] = t; w_slot[i1 * CAP + s1] = v1 / denom; }
        int s2 = atomicAdd(&counts[i2], 1);
        if (s2 < CAP) { tok_slot[i2 * CAP + s2] = t; w_slot[i2 * CAP + s2] = v2 / denom; }
    }
    float g = 0.f;
    const float* xr = X + (size_t)t * DDIM + lane * 16;
    const float* sr = SEG + lane * 16;
#pragma unroll
    for (int j = 0; j < 4; ++j) {
        f32x4 xv = *(const f32x4*)(xr + j * 4);
        f32x4 sv = *(const f32x4*)(sr + j * 4);
#pragma unroll
        for (int q = 0; q < 4; ++q) g += xv[q] * sv[q];
    }
    for (int s = 32; s; s >>= 1) g += __shfl_xor(g, s);
    if (lane == 0) gate_sh[t] = 1.f / (1.f + __expf(-g));
}

// ---------------- fused gate/up GEMM + SwiGLU -> act (bf16), expert + shared in one dispatch
// 1-D grid 1280: f<1024 expert (XCD-pinned: e%8 == f%8), f>=1024 shared (m'%8 == f%8).
// BM=128, BN=64 (g and u each), BK=32, 4 waves (2x2), wave tile 64x32.
// fp32 tiles staged via global_load_lds (async), source-XOR-swizzled, double-buffered;
// converted to bf16 at fragment read. LDS 2 x 32K = 64K -> 2 blocks/CU.
__global__ __launch_bounds__(256, 2) void gateup_all(const float* __restrict__ X,
                                                     const float* __restrict__ GUP,
                                                     const float* __restrict__ SG,
                                                     const float* __restrict__ SU,
                                                     const int* __restrict__ counts,
                                                     const int* __restrict__ tok_slot,
                                                     short* __restrict__ act,
                                                     short* __restrict__ act_sh) {
    __shared__ char smem[2 * 32768];
    int f = blockIdx.x;
    bool expert = f < 1024;
    int e = 0, m0, n0, M;
    const float *Wg, *Wu;
    short* act_out;
    size_t out_base;
    if (expert) {
        int r = f & 7, q = (f >> 3) & 7, n = (f >> 6) & 7, y = f >> 9;
        e = q * 8 + r;                       // XCD(f)=f%8 == e%8 -> expert's blocks share an XCD L2
        n0 = n * 64; m0 = y * 128;
        M = counts[e]; if (M > CAP) M = CAP;
        if (m0 >= M) return;
        const float* base = GUP + (size_t)e * (2 * IDIM) * DDIM;
        Wg = base; Wu = base + (size_t)IDIM * DDIM;
        act_out = act; out_base = (size_t)e * CAP * IDIM;
    } else {
        int g = f - 1024;
        int mp = g & 31, n = g >> 5;         // same-m' blocks share an XCD
        n0 = n * 64; m0 = mp * 128;
        M = T_TOK; Wg = SG; Wu = SU;
        act_out = act_sh; out_base = 0;
    }
    int tid = threadIdx.x, lane = tid & 63, wv = tid >> 6;
    int wm = wv >> 1, wn = wv & 1;

    // staging chunk geometry: slot idx = t*256 + tid, 16 B each.
    // t=0..3: A rows (row = t*32 + tid/8), t=4,5: Bg, t=6,7: Bu.
    int srow8 = tid >> 3;                       // row-within-32 for fp32 chunks
    int scol  = (tid & 7) ^ (srow8 & 7);        // source-swizzled 16B slot
    const float* gp[8];
#pragma unroll
    for (int t = 0; t < 4; ++t) {
        int row = t * 32 + srow8;               // A-tile row 0..127
        int grow;
        if (expert) {
            int rr = m0 + row; if (rr >= M) rr = M - 1;
            grow = tok_slot[e * CAP + rr];
        } else grow = m0 + row;
        gp[t] = X + (size_t)grow * DDIM + scol * 4;
    }
#pragma unroll
    for (int t = 0; t < 2; ++t) {
        int row = t * 32 + srow8;               // B-tile row 0..63
        gp[4 + t] = Wg + (size_t)(n0 + row) * DDIM + scol * 4;
        gp[6 + t] = Wu + (size_t)(n0 + row) * DDIM + scol * 4;
    }

    auto issue = [&](int buf) {
        char* lb = smem + buf * 32768 + wv * 1024;
#pragma unroll
        for (int t = 0; t < 8; ++t) {
            gload16(gp[t], lb + t * 4096);
            gp[t] += 32;                        // next 32-K stage (128 B)
        }
    };

    int fm = lane & 15, s = lane >> 4;
    f32x4 accg[4][2] = {}, accu[4][2] = {};
    auto compute = [&](int buf) {
        const char* bb = smem + buf * 32768;
        bf16x8 bg[2], bu[2];
#pragma unroll
        for (int nt = 0; nt < 2; ++nt) {
            int row = wn * 32 + nt * 16 + fm;
            bg[nt] = frag32(bb + 16384, row, s);
            bu[nt] = frag32(bb + 24576, row, s);
        }
#pragma unroll
        for (int mt = 0; mt < 4; ++mt) {
            int row = wm * 64 + mt * 16 + fm;
            bf16x8 a = frag32(bb, row, s);
#pragma unroll
            for (int nt = 0; nt < 2; ++nt) {
                accg[mt][nt] = __builtin_amdgcn_mfma_f32_16x16x32_bf16(a, bg[nt], accg[mt][nt], 0, 0, 0);
                accu[mt][nt] = __builtin_amdgcn_mfma_f32_16x16x32_bf16(a, bu[nt], accu[mt][nt], 0, 0, 0);
            }
        }
    };

    issue(0);
#pragma unroll 1
    for (int kt = 0; kt < 32; kt += 2) {        // DDIM/32 = 32 stages
        __syncthreads();                        // drains vmcnt -> buf0 ready
        issue(1);
        compute(0);
        __syncthreads();                        // buf1 ready
        if (kt + 2 < 32) issue(0);
        compute(1);
    }

    int frow = (lane >> 4) * 4, fcol = lane & 15;
#pragma unroll
    for (int mt = 0; mt < 4; ++mt)
#pragma unroll
        for (int r = 0; r < 4; ++r) {
            int row = m0 + wm * 64 + mt * 16 + frow + r;
            if (row < M) {
#pragma unroll
                for (int nt = 0; nt < 2; ++nt) {
                    float g = accg[mt][nt][r];
                    float u = accu[mt][nt][r];
                    float a = (g / (1.f + __expf(-g))) * u;      // silu(g)*u
                    act_out[out_base + (size_t)row * IDIM + (n0 + wn * 32 + nt * 16 + fcol)] = f2bs(a);
                }
            }
        }
}

// ---------------- fused down GEMM (A bf16, W fp32), expert + shared, atomicAdd into zeroed out
// 1-D grid 1280, same XCD-pinned decode. BM=128, BN=128, BK=32, 4 waves, wave tile 64x64.
// LDS 2 x 24K = 48K -> 3 blocks/CU.
__global__ __launch_bounds__(256, 3) void down_all(const short* __restrict__ act,
                                                   const short* __restrict__ act_sh,
                                                   const float* __restrict__ DW,
                                                   const float* __restrict__ SD,
                                                   const int* __restrict__ counts,
                                                   const int* __restrict__ tok_slot,
                                                   const float* __restrict__ w_slot,
                                                   const float* __restrict__ gate_sh,
                                                   float* __restrict__ out) {
    __shared__ char smem[2 * 24576];
    const int KD = IDIM;  // 512 both paths
    int f = blockIdx.x;
    bool expert = f < 1024;
    int e = 0, m0, n0, M;
    const short* A;
    const float* W;
    if (expert) {
        int r = f & 7, q = (f >> 3) & 7, n = (f >> 6) & 7, y = f >> 9;
        e = q * 8 + r;
        n0 = n * 128; m0 = y * 128;
        M = counts[e]; if (M > CAP) M = CAP;
        if (m0 >= M) return;
        A = act + (size_t)e * CAP * IDIM;
        W = DW + (size_t)e * DDIM * IDIM;
    } else {
        int g = f - 1024;
        int mp = g & 31, n = g >> 5;
        n0 = n * 128; m0 = mp * 128;
        M = T_TOK; A = act_sh; W = SD;
    }
    int tid = threadIdx.x, lane = tid & 63, wv = tid >> 6;
    int wm = wv >> 1, wn = wv & 1;

    // staging: slot idx = t*256 + tid. t=0,1: A bf16 (4 slots/row, row = t*64 + tid/4);
    // t=2..5: B fp32 (8 slots/row, row = (t-2)*32 + tid/8).
    const short* ap[2];
#pragma unroll
    for (int t = 0; t < 2; ++t) {
        int row = t * 64 + (tid >> 2);
        int col = (tid & 3) ^ ((tid >> 2) & 3);   // source-swizzled 16B slot (4/row)
        ap[t] = A + (size_t)(m0 + row) * KD + col * 8;
    }
    const float* bp[4];
    {
        int srow8 = tid >> 3;
        int col = (tid & 7) ^ (srow8 & 7);
#pragma unroll
        for (int t = 0; t < 4; ++t) {
            int row = t * 32 + srow8;
            bp[t] = W + (size_t)(n0 + row) * KD + col * 4;
        }
    }

    auto issue = [&](int buf) {
        char* lb = smem + buf * 24576 + wv * 1024;
#pragma unroll
        for (int t = 0; t < 2; ++t) {
            gload16(ap[t], lb + t * 4096);
            ap[t] += 32;                        // 32 bf16 = 64 B per stage
        }
#pragma unroll
        for (int t = 0; t < 4; ++t) {
            gload16(bp[t], lb + 8192 + t * 4096);
            bp[t] += 32;                        // 32 fp32 = 128 B per stage
        }
    };

    int fm = lane & 15, s = lane >> 4;
    f32x4 acc[4][4] = {};
    auto compute = [&](int buf) {
        const char* bb = smem + buf * 24576;
        bf16x8 b[4];
#pragma unroll
        for (int nt = 0; nt < 4; ++nt) {
            int row = wn * 64 + nt * 16 + fm;
            b[nt] = frag32(bb + 8192, row, s);
        }
#pragma unroll
        for (int mt = 0; mt < 4; ++mt) {
            int row = wm * 64 + mt * 16 + fm;
            bf16x8 a = *(const bf16x8*)(bb + row * 64 + ((s ^ (row & 3)) << 4));
#pragma unroll
            for (int nt = 0; nt < 4; ++nt)
                acc[mt][nt] = __builtin_amdgcn_mfma_f32_16x16x32_bf16(a, b[nt], acc[mt][nt], 0, 0, 0);
        }
    };

    issue(0);
#pragma unroll 1
    for (int kt = 0; kt < 16; kt += 2) {        // KD/32 = 16 stages
        __syncthreads();
        issue(1);
        compute(0);
        __syncthreads();
        if (kt + 2 < 16) issue(0);
        compute(1);
    }

    int frow = (lane >> 4) * 4, fcol = lane & 15;
#pragma unroll
    for (int mt = 0; mt < 4; ++mt)
#pragma unroll
        for (int r = 0; r < 4; ++r) {
            int row = m0 + wm * 64 + mt * 16 + frow + r;
            if (row >= M) continue;
            float scale; int trow;
            if (expert) { scale = w_slot[e * CAP + row]; trow = tok_slot[e * CAP + row]; }
            else        { scale = gate_sh[row];          trow = row; }
#pragma unroll
            for (int nt = 0; nt < 4; ++nt) {
                int col = n0 + wn * 64 + nt * 16 + fcol;
                atomicAdd(&out[(size_t)trow * DDIM + col], acc[mt][nt][r] * scale);
            }
        }
}

extern "C" void kernel_launch(void* const* d_in, const int* in_sizes, int n_in,
                              void* d_out, int out_size, void* d_ws, size_t ws_size,
                              hipStream_t stream) {
    const float* X   = (const float*)d_in[0];   // hidden_states  [T, D] fp32
    const float* RW  = (const float*)d_in[1];   // router_w       [E, D]
    const float* GUP = (const float*)d_in[2];   // gate_up_proj   [E, 2I, D]
    const float* DW  = (const float*)d_in[3];   // down_proj      [E, D, I]
    const float* SG  = (const float*)d_in[4];   // sh_gate_w      [SI, D]
    const float* SU  = (const float*)d_in[5];   // sh_up_w        [SI, D]
    const float* SD  = (const float*)d_in[6];   // sh_down_w      [D, SI]
    const float* SEG = (const float*)d_in[7];   // sh_expert_gate_w [1, D]
    float* out = (float*)d_out;                 // [T*D] out, then [T*E] probs (fp32)

    char* ws = (char*)d_ws;
    size_t off = 0;
    float* lpart    = (float*)(ws + off); off += (size_t)KZ * T_TOK * NEXP * 4;  // 8 MB
    int*   counts   = (int*)  (ws + off); off += 1024;
    int*   tok_slot = (int*)  (ws + off); off += (size_t)NEXP * CAP * 4;        // 64 KB
    float* w_slot   = (float*)(ws + off); off += (size_t)NEXP * CAP * 4;        // 64 KB
    float* gate_sh  = (float*)(ws + off); off += (size_t)T_TOK * 4;             // 16 KB
    short* act      = (short*)(ws + off); off += (size_t)NEXP * CAP * IDIM * 2; // 16 MB
    short* act_sh   = (short*)(ws + off); off += (size_t)T_TOK * SIDIM * 2;     // 4 MB
    (void)ws_size; (void)in_sizes; (void)n_in; (void)out_size;

    hipMemsetAsync(counts, 0, NEXP * sizeof(int), stream);
    hipMemsetAsync(out, 0, (size_t)T_TOK * DDIM * sizeof(float), stream);  // down_all atomicAdds
    logits_kernel<<<dim3(T_TOK / 64, KZ), 256, 0, stream>>>(X, RW, lpart);
    topk_kernel<<<T_TOK / 4, 256, 0, stream>>>(lpart, X, SEG,
                                               out + (size_t)T_TOK * DDIM,
                                               counts, tok_slot, w_slot, gate_sh);
    gateup_all<<<1280, 256, 0, stream>>>(X, GUP, SG, SU, counts, tok_slot, act, act_sh);
    down_all<<<1280, 256, 0, stream>>>(act, act_sh, DW, SD, counts, tok_slot,
                                       w_slot, gate_sh, out);
}